// Round 12
// baseline (197.521 us; speedup 1.0000x reference)
//
#include <hip/hip_runtime.h>
#include <stdint.h>

// FourierBlock: B=32, D=64, N=128, L=192, M=32 modes.
// Round 12 = fix the mix kernel's occupancy with both measured halves:
//   k1d: DFT, T14 async double-buffer (r10: ~62us) + prologue loads hoisted
//        above the Fb sincos loop (hides cold-start latency). Bit-identical.
//   k2j: i-split staging (69.9KB LDS -> 2 blk/CU, k2h-proven overlap) +
//        block-private full-line Yp epilogue via Yl overlay (r6-verified,
//        kills the RMW amplification k2h measured: WRITE 107MB/33.5MB).
//        Stage reg-batched 8-deep (64KB/block in flight).
//   k3:  r6/r11-verbatim (~30us, write-roofline), reads [n][oq][b][cat][o16].
// ws: Xp 33.5MB @0, Yp 33.5MB @16777216 u16.

typedef __attribute__((ext_vector_type(8))) short short8;
typedef __attribute__((ext_vector_type(4))) float f32x4;
typedef __attribute__((ext_vector_type(4))) unsigned short u16x4;

__device__ __forceinline__ unsigned short f2bf(float f) {
  union { float fv; uint32_t u; } v; v.fv = f;
  uint32_t u = v.u;
  u += 0x7fffu + ((u >> 16) & 1u);          // round-to-nearest-even
  return (unsigned short)(u >> 16);
}

__device__ __forceinline__ f32x4 zero4() { f32x4 z; z[0]=0.f; z[1]=0.f; z[2]=0.f; z[3]=0.f; return z; }

#define TWO_PI_OVER_L (6.283185307179586f / 192.0f)

// ---------------------------------------------------------------------------
// k1d: DFT, async double-buffered. grid 512 = (nq 32, bq 8, ih 2), 512 thr.
// LDS: qB0 [128][200]u16 @0, qB1 @51200, Fb @102400, XE [64][132] @128000.
// Prologue loads issued BEFORE Fb sincos loop (latency hidden under VALU).
// ---------------------------------------------------------------------------
__global__ __launch_bounds__(512, 1)
void k1d_dft(const float* __restrict__ q, unsigned short* __restrict__ Xp) {
  extern __shared__ char smem[];
  unsigned short* qB0 = (unsigned short*)smem;
  unsigned short* qB1 = (unsigned short*)(smem + 51200);
  unsigned short* Fb  = (unsigned short*)(smem + 102400);
  unsigned short* XE  = (unsigned short*)(smem + 128000);
  const int t = threadIdx.x, lane = t & 63, w = t >> 6;
  const int l15 = lane & 15, g = lane >> 4;
  const int bid = blockIdx.x;
  const int ih = bid & 1, bq = (bid >> 1) & 7, nq = bid >> 4;
  const int b0 = bq * 4;

  // stage decode + prologue load issue FIRST (latency hides under Fb loop)
  int srow[12], sqd[12];
#pragma unroll
  for (int j = 0; j < 12; ++j) {
    int fq = (w * 12 + j) * 64 + lane;
    srow[j] = fq / 48;
    sqd[j] = fq - srow[j] * 48;
  }
  size_t qoff[12];
#pragma unroll
  for (int j = 0; j < 12; ++j) {
    int row = srow[j];
    int b = b0 + (row >> 5), i = ih * 32 + (row & 31);
    qoff[j] = ((size_t)((b * 64 + i) * 128)) * 192 + sqd[j] * 4;  // + n*192
  }
  float4 stg[12];
  {
    const int n0 = nq * 4;
#pragma unroll
    for (int j = 0; j < 12; ++j)
      stg[j] = *(const float4*)(q + qoff[j] + (size_t)n0 * 192);
  }

  // DFT basis (VALU-heavy; overlaps the prologue loads above)
  for (int idx = t; idx < 64 * 192; idx += 512) {
    int cat = idx / 192, l = idx - cat * 192;
    int m = cat >> 1;
    int r = (m * l) % 192;
    float ang = (float)r * TWO_PI_OVER_L;
    float v = (cat & 1) ? -__sinf(ang) : __cosf(ang);
    Fb[cat * 200 + l] = f2bf(v);
  }

  // drain prologue -> qB0
#pragma unroll
  for (int j = 0; j < 12; ++j) {
    u16x4 h; h[0] = f2bf(stg[j].x); h[1] = f2bf(stg[j].y);
    h[2] = f2bf(stg[j].z); h[3] = f2bf(stg[j].w);
    *(u16x4*)(qB0 + srow[j] * 200 + sqd[j] * 4) = h;
  }
  __syncthreads();

  for (int nn = 0; nn < 4; ++nn) {
    const int n = nq * 4 + nn;
    unsigned short* cur = (nn & 1) ? qB1 : qB0;
    unsigned short* nxt = (nn & 1) ? qB0 : qB1;

    // T14: issue next phase's loads BEFORE compute
    if (nn < 3) {
#pragma unroll
      for (int j = 0; j < 12; ++j)
        stg[j] = *(const float4*)(q + qoff[j] + (size_t)(n + 1) * 192);
    }

    f32x4 acc[4];
#pragma unroll
    for (int a = 0; a < 4; ++a) acc[a] = zero4();
    const int row = w * 16 + l15;
#pragma unroll
    for (int kc = 0; kc < 6; ++kc) {
      short8 A = *(const short8*)(cur + row * 200 + kc * 32 + g * 8);
#pragma unroll
      for (int nt = 0; nt < 4; ++nt) {
        short8 Bf = *(const short8*)(Fb + (nt * 16 + l15) * 200 + kc * 32 + g * 8);
        acc[nt] = __builtin_amdgcn_mfma_f32_16x16x32_bf16(A, Bf, acc[nt], 0, 0, 0);
      }
    }

    if (nn < 3) {
#pragma unroll
      for (int j = 0; j < 12; ++j) {
        u16x4 h; h[0] = f2bf(stg[j].x); h[1] = f2bf(stg[j].y);
        h[2] = f2bf(stg[j].z); h[3] = f2bf(stg[j].w);
        *(u16x4*)(nxt + srow[j] * 200 + sqd[j] * 4) = h;
      }
    }
    __syncthreads();   // nxt ready; prev XE readers done

    const int b_loc = w >> 1, i_base = (w & 1) * 16 + g * 4;
#pragma unroll
    for (int nt = 0; nt < 4; ++nt) {
      int cat = nt * 16 + l15;
      f32x4 v = acc[nt];
#pragma unroll
      for (int r = 0; r < 4; ++r)
        XE[cat * 132 + b_loc * 32 + i_base + r] = f2bf(v[r]);
    }
    __syncthreads();   // XE ready

#pragma unroll
    for (int cc2 = 0; cc2 < 2; ++cc2) {
      int ch = cc2 * 512 + t;
      int m = ch >> 5, c = (ch >> 4) & 1, g2 = (ch >> 2) & 3, dl = ch & 3;
      short8 v = *(const short8*)(XE + (2 * m + c) * 132 + dl * 32 + g2 * 8);
      int lanep = g2 * 16 + (b0 & 15) + dl;
      int off = n * 131072 + ((((m * 2 + c) * 2 + ih) * 2 + (b0 >> 4)) * 64 + lanep) * 8;
      *(short8*)(Xp + off) = v;
    }
  }
}

// ---------------------------------------------------------------------------
// k2j: complex mix, i-split staging + full-line epilogue.
// grid 512 = (n 128, oq 4), 512 thr, LDS 69888 B -> 2 blk/CU.
// T[c2][i32][o16][m32]: c-stride 17472, i-stride 546, o-stride 34 (u16).
// acc[4 mm][2 cc][2 Mt] persists across i-halves; stage reg-batched 8-deep.
// Epilogue: Yl overlay (b-stride 1036, conflict-free) -> full 64B lines to
// Yp[n][oq][b 32][cat 64][o16] (block-private 64KB region).
// ---------------------------------------------------------------------------
__global__ __launch_bounds__(512, 4)
void k2j_mix(const float* __restrict__ wr, const float* __restrict__ wi,
             const unsigned short* __restrict__ Xp, unsigned short* __restrict__ Yp) {
  extern __shared__ char smem[];
  unsigned short* T = (unsigned short*)smem;
  const int t = threadIdx.x, lane = t & 63, w = t >> 6;
  const int n = blockIdx.x >> 2, oq = blockIdx.x & 3;
  const int ol = lane & 15, il0 = (lane >> 4) * 8, g = lane >> 4;

  f32x4 acc[4][2][2];   // [mm][cc][Mt]
#pragma unroll
  for (int a = 0; a < 4; ++a)
#pragma unroll
    for (int c2 = 0; c2 < 2; ++c2)
#pragma unroll
      for (int b2 = 0; b2 < 2; ++b2) acc[a][c2][b2] = zero4();

  for (int ic = 0; ic < 2; ++ic) {
    if (ic) __syncthreads();               // T readers (ic=0) done before restage
    // stage W[n][ic*32+i][oq*16+o][m] both c: 8192 float4 / 512 thr = 16/thr,
    // reg-batched 8 deep (64KB/block in flight)
#pragma unroll
    for (int jb = 0; jb < 2; ++jb) {
      float4 s[8];
#pragma unroll
      for (int k = 0; k < 8; ++k) {
        int f = (jb * 8 + k) * 512 + t;
        int mg = f & 7, o = (f >> 3) & 15, i = (f >> 7) & 31, c = (f >> 12) & 1;
        s[k] = *(const float4*)((c ? wi : wr) +
                ((n * 64 + ic * 32 + i) * 64 + oq * 16 + o) * 32 + mg * 4);
      }
#pragma unroll
      for (int k = 0; k < 8; ++k) {
        int f = (jb * 8 + k) * 512 + t;
        int mg = f & 7, o = (f >> 3) & 15, i = (f >> 7) & 31, c = (f >> 12) & 1;
        u16x4 h; h[0] = f2bf(s[k].x); h[1] = f2bf(s[k].y); h[2] = f2bf(s[k].z); h[3] = f2bf(s[k].w);
        *(u16x4*)(T + c * 17472 + i * 546 + o * 34 + mg * 4) = h;
      }
    }
    __syncthreads();

#pragma unroll
    for (int mm = 0; mm < 4; ++mm) {
      int m = w * 4 + mm;
      const unsigned short* xb = Xp + n * 131072 + m * 4096 + ic * 1024 + lane * 8;
      short8 Ar0 = *(const short8*)(xb);
      short8 Ar1 = *(const short8*)(xb + 512);
      short8 Ai0 = *(const short8*)(xb + 2048);
      short8 Ai1 = *(const short8*)(xb + 2048 + 512);

      const unsigned short* tb = T + il0 * 546 + ol * 34 + m;
      short8 Br, Bi, nBi;
#pragma unroll
      for (int e = 0; e < 8; ++e) {
        Br[e] = (short)tb[e * 546];
        Bi[e] = (short)tb[17472 + e * 546];
        nBi[e] = Bi[e] ^ (short)0x8000;   // -Wi
      }

      acc[mm][0][0] = __builtin_amdgcn_mfma_f32_16x16x32_bf16(Ar0, Br,  acc[mm][0][0], 0, 0, 0);
      acc[mm][0][0] = __builtin_amdgcn_mfma_f32_16x16x32_bf16(Ai0, nBi, acc[mm][0][0], 0, 0, 0);
      acc[mm][0][1] = __builtin_amdgcn_mfma_f32_16x16x32_bf16(Ar1, Br,  acc[mm][0][1], 0, 0, 0);
      acc[mm][0][1] = __builtin_amdgcn_mfma_f32_16x16x32_bf16(Ai1, nBi, acc[mm][0][1], 0, 0, 0);
      acc[mm][1][0] = __builtin_amdgcn_mfma_f32_16x16x32_bf16(Ar0, Bi,  acc[mm][1][0], 0, 0, 0);
      acc[mm][1][0] = __builtin_amdgcn_mfma_f32_16x16x32_bf16(Ai0, Br,  acc[mm][1][0], 0, 0, 0);
      acc[mm][1][1] = __builtin_amdgcn_mfma_f32_16x16x32_bf16(Ar1, Bi,  acc[mm][1][1], 0, 0, 0);
      acc[mm][1][1] = __builtin_amdgcn_mfma_f32_16x16x32_bf16(Ai1, Br,  acc[mm][1][1], 0, 0, 0);
    }
  }
  __syncthreads();   // all T reads done; Yl overlay

  // epilogue: acc -> Yl[b*1036 + cat*16 + ol]  (conflict-free, r6-verified)
  unsigned short* Yl = (unsigned short*)smem;
#pragma unroll
  for (int mm = 0; mm < 4; ++mm)
#pragma unroll
    for (int cc = 0; cc < 2; ++cc) {
      int cat = 2 * (w * 4 + mm) + cc;
#pragma unroll
      for (int Mt = 0; Mt < 2; ++Mt) {
        f32x4 v = acc[mm][cc][Mt];
#pragma unroll
        for (int r = 0; r < 4; ++r) {
          int b = Mt * 16 + g * 4 + r;
          Yl[b * 1036 + cat * 16 + ol] = f2bf(v[r]);
        }
      }
    }
  __syncthreads();

  // streamout: 32 b x 1024 u16 -> Yp[n][oq][b][cat][o16], full 64B lines
  unsigned short* yblk = Yp + (n * 4 + oq) * 32768;
#pragma unroll
  for (int j = 0; j < 8; ++j) {
    int f = j * 512 + t;
    int b = f >> 7, rem = f & 127;
    const unsigned short* s = Yl + b * 1036 + rem * 8;
    u16x4 lo = *(const u16x4*)(s);
    u16x4 hi = *(const u16x4*)(s + 4);
    short8 v;
    v[0] = (short)lo[0]; v[1] = (short)lo[1]; v[2] = (short)lo[2]; v[3] = (short)lo[3];
    v[4] = (short)hi[0]; v[5] = (short)hi[1]; v[6] = (short)hi[2]; v[7] = (short)hi[3];
    *(short8*)(yblk + b * 1024 + rem * 8) = v;
  }
}

// ---------------------------------------------------------------------------
// K3: iDFT + transposed store (r6/r11 VERBATIM). grid 4096 = (b 32, n 128).
// ---------------------------------------------------------------------------
__global__ __launch_bounds__(256, 4)
void k3_idft(const unsigned short* __restrict__ Yp, float* __restrict__ out) {
  extern __shared__ char smem[];
  unsigned short* Yl = (unsigned short*)smem;        // [cat 64][66]
  float* ol = (float*)(smem + 8448);
  const int t = threadIdx.x, lane = t & 63, w = t >> 6;
  const int n = blockIdx.x & 127, b = blockIdx.x >> 7;

  const unsigned short* ysrc = Yp + (n * 4 * 32 + b) * 1024;   // + oq*32768
#pragma unroll
  for (int j = 0; j < 2; ++j) {
    int f = j * 256 + t;
    int og = f & 1, cat = (f >> 1) & 63, oq = f >> 7;
    short8 v = *(const short8*)(ysrc + oq * 32768 + cat * 16 + og * 8);
    unsigned int* d = (unsigned int*)(Yl + cat * 66 + oq * 16 + og * 8);
    union { short8 s; unsigned int u[4]; } uu; uu.s = v;
    d[0] = uu.u[0]; d[1] = uu.u[1]; d[2] = uu.u[2]; d[3] = uu.u[3];
  }

  short8 Af[3][2];
#pragma unroll
  for (int jm = 0; jm < 3; ++jm) {
    int Mt = w + 4 * jm;
    int lt = Mt * 16 + (lane & 15);
#pragma unroll
    for (int kc = 0; kc < 2; ++kc) {
#pragma unroll
      for (int e = 0; e < 8; ++e) {
        int cat = kc * 32 + (lane >> 4) * 8 + e;
        int m = cat >> 1;
        int r = (m * lt) % 192;
        float ang = (float)r * TWO_PI_OVER_L;
        float coef = (m == 0) ? (1.0f / 192.0f) : (2.0f / 192.0f);
        float v = ((cat & 1) ? -__sinf(ang) : __cosf(ang)) * coef;
        Af[jm][kc][e] = (short)f2bf(v);
      }
    }
  }
  __syncthreads();

  f32x4 acc[3][4];
#pragma unroll
  for (int a = 0; a < 3; ++a)
#pragma unroll
    for (int bq = 0; bq < 4; ++bq) acc[a][bq] = zero4();

#pragma unroll
  for (int kc = 0; kc < 2; ++kc) {
    short8 Bf[4];
#pragma unroll
    for (int nt = 0; nt < 4; ++nt)
#pragma unroll
      for (int e = 0; e < 8; ++e) {
        int cat = kc * 32 + (lane >> 4) * 8 + e;
        Bf[nt][e] = (short)Yl[cat * 66 + nt * 16 + (lane & 15)];
      }
#pragma unroll
    for (int jm = 0; jm < 3; ++jm)
#pragma unroll
      for (int nt = 0; nt < 4; ++nt)
        acc[jm][nt] = __builtin_amdgcn_mfma_f32_16x16x32_bf16(Af[jm][kc], Bf[nt], acc[jm][nt], 0, 0, 0);
  }

#pragma unroll
  for (int jm = 0; jm < 3; ++jm) {
    int Mt = w + 4 * jm;
    int l0 = Mt * 16 + (lane >> 4) * 4;
#pragma unroll
    for (int nt = 0; nt < 4; ++nt) {
      int o = nt * 16 + (lane & 15);
      int lp = l0 ^ ((o & 7) << 2);
      *(f32x4*)(ol + o * 192 + lp) = acc[jm][nt];
    }
  }
  __syncthreads();

  float* dst = out + (b * 64 * 128 + n) * 192;
#pragma unroll
  for (int j = 0; j < 12; ++j) {
    int f = j * 256 + t;
    int o = f / 48, g2 = f - o * 48;
    int lp = g2 * 4;
    int l = lp ^ ((o & 7) << 2);
    f32x4 v = *(const f32x4*)(ol + o * 192 + lp);
    *(f32x4*)(dst + o * (128 * 192) + l) = v;
  }
}

// ---------------------------------------------------------------------------
extern "C" void kernel_launch(void* const* d_in, const int* in_sizes, int n_in,
                              void* d_out, int out_size, void* d_ws, size_t ws_size,
                              hipStream_t stream) {
  const float* q  = (const float*)d_in[0];
  const float* wr = (const float*)d_in[1];
  const float* wi = (const float*)d_in[2];
  float* out = (float*)d_out;

  unsigned short* Xp = (unsigned short*)d_ws;            // 33.5 MB
  unsigned short* Yp = Xp + 16777216;                    // 33.5 MB

  hipFuncSetAttribute((const void*)k1d_dft, hipFuncAttributeMaxDynamicSharedMemorySize, 144896);
  hipFuncSetAttribute((const void*)k2j_mix, hipFuncAttributeMaxDynamicSharedMemorySize, 69888);
  hipFuncSetAttribute((const void*)k3_idft, hipFuncAttributeMaxDynamicSharedMemorySize, 57600);

  k1d_dft<<<dim3(512), dim3(512), 144896, stream>>>(q, Xp);
  k2j_mix<<<dim3(512), dim3(512), 69888, stream>>>(wr, wi, Xp, Yp);
  k3_idft<<<dim3(4096), dim3(256), 57600, stream>>>(Yp, out);
}

// Round 13
// 185.874 us; speedup vs baseline: 1.0627x; 1.0627x over previous
//
#include <hip/hip_runtime.h>
#include <stdint.h>

// FourierBlock: B=32, D=64, N=128, L=192, M=32 modes.
// Round 13 = composition of per-stage measured winners:
//   k1d: DFT, T14 async double-buffered staging (r10 REP-measured ~62us).
//   k0:  W fp32 -> Wp bf16 frag-packed, streaming (r3; k0+k2 pair = 68us).
//   k2:  pure streaming complex mix, frag operands from global, tiny LDS
//        epilogue -> full-line Yp[n][b][cat][o] stores (r3 verbatim).
//   k3:  iDFT, swizzled LDS transpose, coalesced out stores (r4 verbatim).
// ws: Xp 33.5MB @0, Yp 33.5MB @16777216 u16, Wp 67MB @33554432 u16.

typedef __attribute__((ext_vector_type(8))) short short8;
typedef __attribute__((ext_vector_type(4))) float f32x4;
typedef __attribute__((ext_vector_type(4))) unsigned short u16x4;

__device__ __forceinline__ unsigned short f2bf(float f) {
  union { float fv; uint32_t u; } v; v.fv = f;
  uint32_t u = v.u;
  u += 0x7fffu + ((u >> 16) & 1u);          // round-to-nearest-even
  return (unsigned short)(u >> 16);
}

__device__ __forceinline__ f32x4 zero4() { f32x4 z; z[0]=0.f; z[1]=0.f; z[2]=0.f; z[3]=0.f; return z; }

#define TWO_PI_OVER_L (6.283185307179586f / 192.0f)

// ---------------------------------------------------------------------------
// k1d: DFT, async double-buffered. grid 512 = (nq 32, bq 8, ih 2), 512 thr.
// LDS: qB0 [128][200]u16 @0, qB1 @51200, Fb @102400, XE [64][132] @128000.
// ---------------------------------------------------------------------------
__global__ __launch_bounds__(512, 1)
void k1d_dft(const float* __restrict__ q, unsigned short* __restrict__ Xp) {
  extern __shared__ char smem[];
  unsigned short* qB0 = (unsigned short*)smem;
  unsigned short* qB1 = (unsigned short*)(smem + 51200);
  unsigned short* Fb  = (unsigned short*)(smem + 102400);
  unsigned short* XE  = (unsigned short*)(smem + 128000);
  const int t = threadIdx.x, lane = t & 63, w = t >> 6;
  const int l15 = lane & 15, g = lane >> 4;
  const int bid = blockIdx.x;
  const int ih = bid & 1, bq = (bid >> 1) & 7, nq = bid >> 4;
  const int b0 = bq * 4;

  int srow[12], sqd[12];
#pragma unroll
  for (int j = 0; j < 12; ++j) {
    int fq = (w * 12 + j) * 64 + lane;
    srow[j] = fq / 48;
    sqd[j] = fq - srow[j] * 48;
  }
  size_t qoff[12];
#pragma unroll
  for (int j = 0; j < 12; ++j) {
    int row = srow[j];
    int b = b0 + (row >> 5), i = ih * 32 + (row & 31);
    qoff[j] = ((size_t)((b * 64 + i) * 128)) * 192 + sqd[j] * 4;  // + n*192
  }
  float4 stg[12];
  {
    const int n0 = nq * 4;
#pragma unroll
    for (int j = 0; j < 12; ++j)
      stg[j] = *(const float4*)(q + qoff[j] + (size_t)n0 * 192);
  }

  // DFT basis (VALU-heavy; overlaps the prologue loads above)
  for (int idx = t; idx < 64 * 192; idx += 512) {
    int cat = idx / 192, l = idx - cat * 192;
    int m = cat >> 1;
    int r = (m * l) % 192;
    float ang = (float)r * TWO_PI_OVER_L;
    float v = (cat & 1) ? -__sinf(ang) : __cosf(ang);
    Fb[cat * 200 + l] = f2bf(v);
  }

#pragma unroll
  for (int j = 0; j < 12; ++j) {
    u16x4 h; h[0] = f2bf(stg[j].x); h[1] = f2bf(stg[j].y);
    h[2] = f2bf(stg[j].z); h[3] = f2bf(stg[j].w);
    *(u16x4*)(qB0 + srow[j] * 200 + sqd[j] * 4) = h;
  }
  __syncthreads();

  for (int nn = 0; nn < 4; ++nn) {
    const int n = nq * 4 + nn;
    unsigned short* cur = (nn & 1) ? qB1 : qB0;
    unsigned short* nxt = (nn & 1) ? qB0 : qB1;

    if (nn < 3) {
#pragma unroll
      for (int j = 0; j < 12; ++j)
        stg[j] = *(const float4*)(q + qoff[j] + (size_t)(n + 1) * 192);
    }

    f32x4 acc[4];
#pragma unroll
    for (int a = 0; a < 4; ++a) acc[a] = zero4();
    const int row = w * 16 + l15;
#pragma unroll
    for (int kc = 0; kc < 6; ++kc) {
      short8 A = *(const short8*)(cur + row * 200 + kc * 32 + g * 8);
#pragma unroll
      for (int nt = 0; nt < 4; ++nt) {
        short8 Bf = *(const short8*)(Fb + (nt * 16 + l15) * 200 + kc * 32 + g * 8);
        acc[nt] = __builtin_amdgcn_mfma_f32_16x16x32_bf16(A, Bf, acc[nt], 0, 0, 0);
      }
    }

    if (nn < 3) {
#pragma unroll
      for (int j = 0; j < 12; ++j) {
        u16x4 h; h[0] = f2bf(stg[j].x); h[1] = f2bf(stg[j].y);
        h[2] = f2bf(stg[j].z); h[3] = f2bf(stg[j].w);
        *(u16x4*)(nxt + srow[j] * 200 + sqd[j] * 4) = h;
      }
    }
    __syncthreads();   // nxt ready; prev XE readers done

    const int b_loc = w >> 1, i_base = (w & 1) * 16 + g * 4;
#pragma unroll
    for (int nt = 0; nt < 4; ++nt) {
      int cat = nt * 16 + l15;
      f32x4 v = acc[nt];
#pragma unroll
      for (int r = 0; r < 4; ++r)
        XE[cat * 132 + b_loc * 32 + i_base + r] = f2bf(v[r]);
    }
    __syncthreads();   // XE ready

#pragma unroll
    for (int cc2 = 0; cc2 < 2; ++cc2) {
      int ch = cc2 * 512 + t;
      int m = ch >> 5, c = (ch >> 4) & 1, g2 = (ch >> 2) & 3, dl = ch & 3;
      short8 v = *(const short8*)(XE + (2 * m + c) * 132 + dl * 32 + g2 * 8);
      int lanep = g2 * 16 + (b0 & 15) + dl;
      int off = n * 131072 + ((((m * 2 + c) * 2 + ih) * 2 + (b0 >> 4)) * 64 + lanep) * 8;
      *(short8*)(Xp + off) = v;
    }
  }
}

// ---------------------------------------------------------------------------
// K0: W repack (r3 VERBATIM). grid 2048 = (n128, c2, nt4, ic2), 256 thr.
// ---------------------------------------------------------------------------
__global__ __launch_bounds__(256, 4)
void k0_repack(const float* __restrict__ wr, const float* __restrict__ wi,
               unsigned short* __restrict__ Wp) {
  __shared__ unsigned short T[32 * 16 * 36];   // 36864 B
  const int t = threadIdx.x;
  const int bid = blockIdx.x;
  const int ic = bid & 1, nt = (bid >> 1) & 3, c = (bid >> 3) & 1, n = bid >> 4;
  const float* src = (c ? wi : wr) + ((n * 64 + ic * 32) * 64 + nt * 16) * 32;

#pragma unroll
  for (int j = 0; j < 16; ++j) {
    int f = j * 256 + t;                       // float4 units [0,4096)
    int mg = f & 7, o = (f >> 3) & 15, i = f >> 7;
    float4 v = *(const float4*)(src + i * 2048 + o * 32 + mg * 4);
    u16x4 h; h[0] = f2bf(v.x); h[1] = f2bf(v.y); h[2] = f2bf(v.z); h[3] = f2bf(v.w);
    *(u16x4*)(T + (i * 16 + o) * 36 + mg * 4) = h;
  }
  __syncthreads();

  unsigned short* dst = Wp + ((((n * 32) * 2 + c) * 4 + nt) * 2 + ic) * 512;
#pragma unroll
  for (int j = 0; j < 8; ++j) {
    int f = j * 256 + t;                       // (m, lane-slot) [0,2048)
    int m = f >> 6, lidx = f & 63;
    int il0 = (lidx >> 4) * 8, ol = lidx & 15;
    short8 v;
#pragma unroll
    for (int e = 0; e < 8; ++e)
      v[e] = (short)T[((il0 + e) * 16 + ol) * 36 + m];
    *(short8*)(dst + m * 8192 + lidx * 8) = v;
  }
}

// ---------------------------------------------------------------------------
// K2: streaming complex mix (r3 VERBATIM). grid 4096 = (n128, m32), 256 thr.
// ---------------------------------------------------------------------------
__global__ __launch_bounds__(256, 4)
void k2_mix(const unsigned short* __restrict__ Wp, const unsigned short* __restrict__ Xp,
            unsigned short* __restrict__ Yp) {
  __shared__ unsigned short Yl[32 * 132];      // row stride 132 u16
  const int t = threadIdx.x, lane = t & 63, w = t >> 6;
  const int n = blockIdx.x >> 5, m = blockIdx.x & 31;

  const unsigned short* xb = Xp + n * 131072 + m * 4096 + lane * 8;
  short8 Ar[2][2], Ai[2][2];
#pragma unroll
  for (int ic = 0; ic < 2; ++ic)
#pragma unroll
    for (int Mt = 0; Mt < 2; ++Mt) {
      Ar[ic][Mt] = *(const short8*)(xb + (ic * 2 + Mt) * 512);
      Ai[ic][Mt] = *(const short8*)(xb + 2048 + (ic * 2 + Mt) * 512);
    }

  const unsigned short* wb = Wp + (n * 32 + m) * 8192 + w * 1024 + lane * 8;
  short8 Br[2], Bi[2], nBi[2];
#pragma unroll
  for (int ic = 0; ic < 2; ++ic) {
    Br[ic] = *(const short8*)(wb + ic * 512);
    Bi[ic] = *(const short8*)(wb + 4096 + ic * 512);
#pragma unroll
    for (int e = 0; e < 8; ++e) nBi[ic][e] = Bi[ic][e] ^ (short)0x8000;   // -Wi
  }

  f32x4 acc[2][2];  // [cc][Mt]
#pragma unroll
  for (int a = 0; a < 2; ++a)
#pragma unroll
    for (int b2 = 0; b2 < 2; ++b2) acc[a][b2] = zero4();

#pragma unroll
  for (int ic = 0; ic < 2; ++ic)
#pragma unroll
    for (int Mt = 0; Mt < 2; ++Mt) {
      acc[0][Mt] = __builtin_amdgcn_mfma_f32_16x16x32_bf16(Ar[ic][Mt], Br[ic],  acc[0][Mt], 0, 0, 0);
      acc[0][Mt] = __builtin_amdgcn_mfma_f32_16x16x32_bf16(Ai[ic][Mt], nBi[ic], acc[0][Mt], 0, 0, 0);
      acc[1][Mt] = __builtin_amdgcn_mfma_f32_16x16x32_bf16(Ar[ic][Mt], Bi[ic],  acc[1][Mt], 0, 0, 0);
      acc[1][Mt] = __builtin_amdgcn_mfma_f32_16x16x32_bf16(Ai[ic][Mt], Br[ic],  acc[1][Mt], 0, 0, 0);
    }

  // C-frags -> LDS: Yl[b*132 + cc*64 + o]
  const int ol = lane & 15, g = lane >> 4;
#pragma unroll
  for (int cc = 0; cc < 2; ++cc)
#pragma unroll
    for (int Mt = 0; Mt < 2; ++Mt) {
      f32x4 v = acc[cc][Mt];
#pragma unroll
      for (int r = 0; r < 4; ++r) {
        int b = Mt * 16 + g * 4 + r;
        Yl[b * 132 + cc * 64 + w * 16 + ol] = f2bf(v[r]);
      }
    }
  __syncthreads();

  // LDS -> Yp[n][b][2m+cc][o]: 512 short8's -> exactly 2 iterations
  unsigned short* yb = Yp + n * 131072 + m * 128;
#pragma unroll
  for (int j = 0; j < 2; ++j) {
    int f = j * 256 + t;
    int b = f >> 4, rem = f & 15;
    const unsigned short* p = Yl + b * 132 + rem * 8;
    u16x4 lo = *(const u16x4*)(p);
    u16x4 hi = *(const u16x4*)(p + 4);
    short8 v;
    v[0] = (short)lo[0]; v[1] = (short)lo[1]; v[2] = (short)lo[2]; v[3] = (short)lo[3];
    v[4] = (short)hi[0]; v[5] = (short)hi[1]; v[6] = (short)hi[2]; v[7] = (short)hi[3];
    *(short8*)(yb + b * 4096 + rem * 8) = v;
  }
}

// ---------------------------------------------------------------------------
// K3: iDFT + transposed store (r4 VERBATIM). grid 4096 = (b 32, n 128), 256 thr.
// ---------------------------------------------------------------------------
__global__ __launch_bounds__(256, 4)
void k3_idft(const unsigned short* __restrict__ Yp, float* __restrict__ out) {
  extern __shared__ char smem[];
  unsigned short* Yl = (unsigned short*)smem;
  float* ol = (float*)(smem + 8192);
  const int t = threadIdx.x, lane = t & 63, w = t >> 6;
  const int n = blockIdx.x & 127, b = blockIdx.x >> 7;

  const unsigned short* ysrc = Yp + (n * 32 + b) * 4096;
#pragma unroll
  for (int j = 0; j < 2; ++j) {
    int f = j * 256 + t;
    *(short8*)(Yl + f * 8) = *(const short8*)(ysrc + f * 8);
  }

  short8 Af[3][2];
#pragma unroll
  for (int jm = 0; jm < 3; ++jm) {
    int Mt = w + 4 * jm;
    int lt = Mt * 16 + (lane & 15);
#pragma unroll
    for (int kc = 0; kc < 2; ++kc) {
#pragma unroll
      for (int e = 0; e < 8; ++e) {
        int cat = kc * 32 + (lane >> 4) * 8 + e;
        int m = cat >> 1;
        int r = (m * lt) % 192;
        float ang = (float)r * TWO_PI_OVER_L;
        float coef = (m == 0) ? (1.0f / 192.0f) : (2.0f / 192.0f);
        float v = ((cat & 1) ? -__sinf(ang) : __cosf(ang)) * coef;
        Af[jm][kc][e] = (short)f2bf(v);
      }
    }
  }
  __syncthreads();

  f32x4 acc[3][4];
#pragma unroll
  for (int a = 0; a < 3; ++a)
#pragma unroll
    for (int bq = 0; bq < 4; ++bq) acc[a][bq] = zero4();

#pragma unroll
  for (int kc = 0; kc < 2; ++kc) {
    short8 Bf[4];
#pragma unroll
    for (int nt = 0; nt < 4; ++nt)
#pragma unroll
      for (int e = 0; e < 8; ++e) {
        int cat = kc * 32 + (lane >> 4) * 8 + e;
        Bf[nt][e] = (short)Yl[cat * 64 + nt * 16 + (lane & 15)];
      }
#pragma unroll
    for (int jm = 0; jm < 3; ++jm)
#pragma unroll
      for (int nt = 0; nt < 4; ++nt)
        acc[jm][nt] = __builtin_amdgcn_mfma_f32_16x16x32_bf16(Af[jm][kc], Bf[nt], acc[jm][nt], 0, 0, 0);
  }

#pragma unroll
  for (int jm = 0; jm < 3; ++jm) {
    int Mt = w + 4 * jm;
    int l0 = Mt * 16 + (lane >> 4) * 4;
#pragma unroll
    for (int nt = 0; nt < 4; ++nt) {
      int o = nt * 16 + (lane & 15);
      int lp = l0 ^ ((o & 7) << 2);
      *(f32x4*)(ol + o * 192 + lp) = acc[jm][nt];
    }
  }
  __syncthreads();

  float* dst = out + (b * 64 * 128 + n) * 192;
#pragma unroll
  for (int j = 0; j < 12; ++j) {
    int f = j * 256 + t;
    int o = f / 48, g2 = f - o * 48;
    int lp = g2 * 4;
    int l = lp ^ ((o & 7) << 2);
    f32x4 v = *(const f32x4*)(ol + o * 192 + lp);
    *(f32x4*)(dst + o * (128 * 192) + l) = v;
  }
}

// ---------------------------------------------------------------------------
extern "C" void kernel_launch(void* const* d_in, const int* in_sizes, int n_in,
                              void* d_out, int out_size, void* d_ws, size_t ws_size,
                              hipStream_t stream) {
  const float* q  = (const float*)d_in[0];
  const float* wr = (const float*)d_in[1];
  const float* wi = (const float*)d_in[2];
  float* out = (float*)d_out;

  unsigned short* Xp = (unsigned short*)d_ws;            // 33.5 MB
  unsigned short* Yp = Xp + 16777216;                    // 33.5 MB
  unsigned short* Wp = Xp + 33554432;                    // 67 MB

  hipFuncSetAttribute((const void*)k1d_dft, hipFuncAttributeMaxDynamicSharedMemorySize, 144896);
  hipFuncSetAttribute((const void*)k3_idft, hipFuncAttributeMaxDynamicSharedMemorySize, 57344);

  k1d_dft<<<dim3(512), dim3(512), 144896, stream>>>(q, Xp);
  k0_repack<<<dim3(2048), dim3(256), 0, stream>>>(wr, wi, Wp);
  k2_mix<<<dim3(4096), dim3(256), 0, stream>>>(Wp, Xp, Yp);
  k3_idft<<<dim3(4096), dim3(256), 57344, stream>>>(Yp, out);
}

// Round 14
// 179.350 us; speedup vs baseline: 1.1013x; 1.0364x over previous
//
#include <hip/hip_runtime.h>
#include <stdint.h>

// FourierBlock: B=32, D=64, N=128, L=192, M=32 modes.
// Round 14 = r11 base (best, 173.8us) with the occupancy lever tested in
// ISOLATION on the mix kernel:
//   k1d: DFT, T14 async double-buffered staging (r12/r13 verbatim, ~62us).
//   k2m: k2i with m-split ONLY: grid 1024 = (n,oq,mh), LDS [c2][i64][o16][m16]
//        = 74240 B -> 2 blk/CU. Same single stage pass, same barrier count,
//        same epilogue, same accumulation order (bit-identical output).
//   k3:  r11 verbatim (reads Yp[n][oq][b][cat][o16], ~30us write-roofline).
// ws: Xp 33.5MB @0, Yp 33.5MB @16777216 u16.

typedef __attribute__((ext_vector_type(8))) short short8;
typedef __attribute__((ext_vector_type(4))) float f32x4;
typedef __attribute__((ext_vector_type(4))) unsigned short u16x4;

__device__ __forceinline__ unsigned short f2bf(float f) {
  union { float fv; uint32_t u; } v; v.fv = f;
  uint32_t u = v.u;
  u += 0x7fffu + ((u >> 16) & 1u);          // round-to-nearest-even
  return (unsigned short)(u >> 16);
}

__device__ __forceinline__ f32x4 zero4() { f32x4 z; z[0]=0.f; z[1]=0.f; z[2]=0.f; z[3]=0.f; return z; }

#define TWO_PI_OVER_L (6.283185307179586f / 192.0f)

// ---------------------------------------------------------------------------
// k1d: DFT, async double-buffered. grid 512 = (nq 32, bq 8, ih 2), 512 thr.
// LDS: qB0 [128][200]u16 @0, qB1 @51200, Fb @102400, XE [64][132] @128000.
// ---------------------------------------------------------------------------
__global__ __launch_bounds__(512, 1)
void k1d_dft(const float* __restrict__ q, unsigned short* __restrict__ Xp) {
  extern __shared__ char smem[];
  unsigned short* qB0 = (unsigned short*)smem;
  unsigned short* qB1 = (unsigned short*)(smem + 51200);
  unsigned short* Fb  = (unsigned short*)(smem + 102400);
  unsigned short* XE  = (unsigned short*)(smem + 128000);
  const int t = threadIdx.x, lane = t & 63, w = t >> 6;
  const int l15 = lane & 15, g = lane >> 4;
  const int bid = blockIdx.x;
  const int ih = bid & 1, bq = (bid >> 1) & 7, nq = bid >> 4;
  const int b0 = bq * 4;

  int srow[12], sqd[12];
#pragma unroll
  for (int j = 0; j < 12; ++j) {
    int fq = (w * 12 + j) * 64 + lane;
    srow[j] = fq / 48;
    sqd[j] = fq - srow[j] * 48;
  }
  size_t qoff[12];
#pragma unroll
  for (int j = 0; j < 12; ++j) {
    int row = srow[j];
    int b = b0 + (row >> 5), i = ih * 32 + (row & 31);
    qoff[j] = ((size_t)((b * 64 + i) * 128)) * 192 + sqd[j] * 4;  // + n*192
  }
  float4 stg[12];
  {
    const int n0 = nq * 4;
#pragma unroll
    for (int j = 0; j < 12; ++j)
      stg[j] = *(const float4*)(q + qoff[j] + (size_t)n0 * 192);
  }

  // DFT basis (VALU-heavy; overlaps the prologue loads above)
  for (int idx = t; idx < 64 * 192; idx += 512) {
    int cat = idx / 192, l = idx - cat * 192;
    int m = cat >> 1;
    int r = (m * l) % 192;
    float ang = (float)r * TWO_PI_OVER_L;
    float v = (cat & 1) ? -__sinf(ang) : __cosf(ang);
    Fb[cat * 200 + l] = f2bf(v);
  }

#pragma unroll
  for (int j = 0; j < 12; ++j) {
    u16x4 h; h[0] = f2bf(stg[j].x); h[1] = f2bf(stg[j].y);
    h[2] = f2bf(stg[j].z); h[3] = f2bf(stg[j].w);
    *(u16x4*)(qB0 + srow[j] * 200 + sqd[j] * 4) = h;
  }
  __syncthreads();

  for (int nn = 0; nn < 4; ++nn) {
    const int n = nq * 4 + nn;
    unsigned short* cur = (nn & 1) ? qB1 : qB0;
    unsigned short* nxt = (nn & 1) ? qB0 : qB1;

    if (nn < 3) {
#pragma unroll
      for (int j = 0; j < 12; ++j)
        stg[j] = *(const float4*)(q + qoff[j] + (size_t)(n + 1) * 192);
    }

    f32x4 acc[4];
#pragma unroll
    for (int a = 0; a < 4; ++a) acc[a] = zero4();
    const int row = w * 16 + l15;
#pragma unroll
    for (int kc = 0; kc < 6; ++kc) {
      short8 A = *(const short8*)(cur + row * 200 + kc * 32 + g * 8);
#pragma unroll
      for (int nt = 0; nt < 4; ++nt) {
        short8 Bf = *(const short8*)(Fb + (nt * 16 + l15) * 200 + kc * 32 + g * 8);
        acc[nt] = __builtin_amdgcn_mfma_f32_16x16x32_bf16(A, Bf, acc[nt], 0, 0, 0);
      }
    }

    if (nn < 3) {
#pragma unroll
      for (int j = 0; j < 12; ++j) {
        u16x4 h; h[0] = f2bf(stg[j].x); h[1] = f2bf(stg[j].y);
        h[2] = f2bf(stg[j].z); h[3] = f2bf(stg[j].w);
        *(u16x4*)(nxt + srow[j] * 200 + sqd[j] * 4) = h;
      }
    }
    __syncthreads();   // nxt ready; prev XE readers done

    const int b_loc = w >> 1, i_base = (w & 1) * 16 + g * 4;
#pragma unroll
    for (int nt = 0; nt < 4; ++nt) {
      int cat = nt * 16 + l15;
      f32x4 v = acc[nt];
#pragma unroll
      for (int r = 0; r < 4; ++r)
        XE[cat * 132 + b_loc * 32 + i_base + r] = f2bf(v[r]);
    }
    __syncthreads();   // XE ready

#pragma unroll
    for (int cc2 = 0; cc2 < 2; ++cc2) {
      int ch = cc2 * 512 + t;
      int m = ch >> 5, c = (ch >> 4) & 1, g2 = (ch >> 2) & 3, dl = ch & 3;
      short8 v = *(const short8*)(XE + (2 * m + c) * 132 + dl * 32 + g2 * 8);
      int lanep = g2 * 16 + (b0 & 15) + dl;
      int off = n * 131072 + ((((m * 2 + c) * 2 + ih) * 2 + (b0 >> 4)) * 64 + lanep) * 8;
      *(short8*)(Xp + off) = v;
    }
  }
}

// ---------------------------------------------------------------------------
// k2m: fused W-stage + complex mix, m-split for 2 blk/CU.
// grid 1024 = (n 128, oq 4, mh 2), 512 thr. LDS 74240 B.
// T[c2][i64][o16][m16]: c-stride 18560, i-stride 290, o-stride 18 (u16).
// Wave w handles m_loc = w*2 + {0,1}  (m_global = mh*16 + m_loc).
// Same stage/barrier/compute/epilogue structure as k2i (r11).
// ---------------------------------------------------------------------------
#define M_OSTRIDE 18
#define M_ISTRIDE 290         // 16*18 + 2
#define M_CSTRIDE 18560       // 64*290
__global__ __launch_bounds__(512, 4)
void k2m_mix(const float* __restrict__ wr, const float* __restrict__ wi,
             const unsigned short* __restrict__ Xp, unsigned short* __restrict__ Yp) {
  extern __shared__ char smem[];
  unsigned short* T = (unsigned short*)smem;
  const int t = threadIdx.x, lane = t & 63, w = t >> 6;
  const int mh = blockIdx.x & 1, oq = (blockIdx.x >> 1) & 3, n = blockIdx.x >> 3;
  const int ol = lane & 15, il0 = (lane >> 4) * 8;

  // stage W[n][i 0..63][oq*16+o][mh*16 + 0..15][c2] fp32 -> bf16 LDS (16/thr)
#pragma unroll
  for (int j = 0; j < 16; ++j) {
    int f = j * 512 + t;
    int mg = f & 3, o = (f >> 2) & 15, i = (f >> 6) & 63, c = (f >> 12) & 1;
    const float* src = (c ? wi : wr) + ((n * 64 + i) * 64 + oq * 16 + o) * 32 + mh * 16 + mg * 4;
    float4 v = *(const float4*)src;
    u16x4 h; h[0] = f2bf(v.x); h[1] = f2bf(v.y); h[2] = f2bf(v.z); h[3] = f2bf(v.w);
    *(u16x4*)(T + c * M_CSTRIDE + i * M_ISTRIDE + o * M_OSTRIDE + mg * 4) = h;
  }
  __syncthreads();

  unsigned short* yblk = Yp + (n * 4 + oq) * 32768;   // [b32][cat64][o16]

#pragma unroll
  for (int mm = 0; mm < 2; ++mm) {
    int m_loc = w * 2 + mm;
    int m = mh * 16 + m_loc;
    f32x4 acc[2][2];  // [cc][Mt]
#pragma unroll
    for (int a = 0; a < 2; ++a)
#pragma unroll
      for (int b2 = 0; b2 < 2; ++b2) acc[a][b2] = zero4();

#pragma unroll
    for (int ic = 0; ic < 2; ++ic) {
      const unsigned short* xb = Xp + n * 131072 + m * 4096 + ic * 1024 + lane * 8;
      short8 Ar0 = *(const short8*)(xb);
      short8 Ar1 = *(const short8*)(xb + 512);
      short8 Ai0 = *(const short8*)(xb + 2048);
      short8 Ai1 = *(const short8*)(xb + 2048 + 512);

      const unsigned short* tb = T + (ic * 32 + il0) * M_ISTRIDE + ol * M_OSTRIDE + m_loc;
      short8 Br, Bi, nBi;
#pragma unroll
      for (int e = 0; e < 8; ++e) {
        Br[e] = (short)tb[e * M_ISTRIDE];
        Bi[e] = (short)tb[M_CSTRIDE + e * M_ISTRIDE];
        nBi[e] = Bi[e] ^ (short)0x8000;   // -Wi
      }

      acc[0][0] = __builtin_amdgcn_mfma_f32_16x16x32_bf16(Ar0, Br,  acc[0][0], 0, 0, 0);
      acc[0][0] = __builtin_amdgcn_mfma_f32_16x16x32_bf16(Ai0, nBi, acc[0][0], 0, 0, 0);
      acc[0][1] = __builtin_amdgcn_mfma_f32_16x16x32_bf16(Ar1, Br,  acc[0][1], 0, 0, 0);
      acc[0][1] = __builtin_amdgcn_mfma_f32_16x16x32_bf16(Ai1, nBi, acc[0][1], 0, 0, 0);
      acc[1][0] = __builtin_amdgcn_mfma_f32_16x16x32_bf16(Ar0, Bi,  acc[1][0], 0, 0, 0);
      acc[1][0] = __builtin_amdgcn_mfma_f32_16x16x32_bf16(Ai0, Br,  acc[1][0], 0, 0, 0);
      acc[1][1] = __builtin_amdgcn_mfma_f32_16x16x32_bf16(Ar1, Bi,  acc[1][1], 0, 0, 0);
      acc[1][1] = __builtin_amdgcn_mfma_f32_16x16x32_bf16(Ai1, Br,  acc[1][1], 0, 0, 0);
    }

    // epilogue: Yp[n][oq][b][2m+cc][ol] -- same as k2i (64B line per cat pair)
    const int g = lane >> 4;
#pragma unroll
    for (int Mt = 0; Mt < 2; ++Mt)
#pragma unroll
      for (int r = 0; r < 4; ++r) {
        int b = Mt * 16 + g * 4 + r;
        unsigned short* yb = yblk + b * 1024 + (2 * m) * 16 + ol;
        yb[0]  = f2bf(acc[0][Mt][r]);      // cat = 2m
        yb[16] = f2bf(acc[1][Mt][r]);      // cat = 2m+1 (same 64B line)
      }
  }
}

// ---------------------------------------------------------------------------
// K3: iDFT + transposed store (r11 VERBATIM). grid 4096 = (b 32, n 128).
// Stages Yp[n][oq][b][cat][o16] -> Yl[cat][66]; swizzled out-LDS; full-line out.
// ---------------------------------------------------------------------------
__global__ __launch_bounds__(256, 4)
void k3_idft(const unsigned short* __restrict__ Yp, float* __restrict__ out) {
  extern __shared__ char smem[];
  unsigned short* Yl = (unsigned short*)smem;        // [cat 64][66]
  float* ol = (float*)(smem + 8448);
  const int t = threadIdx.x, lane = t & 63, w = t >> 6;
  const int n = blockIdx.x & 127, b = blockIdx.x >> 7;

  const unsigned short* ysrc = Yp + (n * 4 * 32 + b) * 1024;   // + oq*32768
#pragma unroll
  for (int j = 0; j < 2; ++j) {
    int f = j * 256 + t;
    int og = f & 1, cat = (f >> 1) & 63, oq = f >> 7;
    short8 v = *(const short8*)(ysrc + oq * 32768 + cat * 16 + og * 8);
    unsigned int* d = (unsigned int*)(Yl + cat * 66 + oq * 16 + og * 8);
    union { short8 s; unsigned int u[4]; } uu; uu.s = v;
    d[0] = uu.u[0]; d[1] = uu.u[1]; d[2] = uu.u[2]; d[3] = uu.u[3];
  }

  short8 Af[3][2];
#pragma unroll
  for (int jm = 0; jm < 3; ++jm) {
    int Mt = w + 4 * jm;
    int lt = Mt * 16 + (lane & 15);
#pragma unroll
    for (int kc = 0; kc < 2; ++kc) {
#pragma unroll
      for (int e = 0; e < 8; ++e) {
        int cat = kc * 32 + (lane >> 4) * 8 + e;
        int m = cat >> 1;
        int r = (m * lt) % 192;
        float ang = (float)r * TWO_PI_OVER_L;
        float coef = (m == 0) ? (1.0f / 192.0f) : (2.0f / 192.0f);
        float v = ((cat & 1) ? -__sinf(ang) : __cosf(ang)) * coef;
        Af[jm][kc][e] = (short)f2bf(v);
      }
    }
  }
  __syncthreads();

  f32x4 acc[3][4];
#pragma unroll
  for (int a = 0; a < 3; ++a)
#pragma unroll
    for (int bq = 0; bq < 4; ++bq) acc[a][bq] = zero4();

#pragma unroll
  for (int kc = 0; kc < 2; ++kc) {
    short8 Bf[4];
#pragma unroll
    for (int nt = 0; nt < 4; ++nt)
#pragma unroll
      for (int e = 0; e < 8; ++e) {
        int cat = kc * 32 + (lane >> 4) * 8 + e;
        Bf[nt][e] = (short)Yl[cat * 66 + nt * 16 + (lane & 15)];
      }
#pragma unroll
    for (int jm = 0; jm < 3; ++jm)
#pragma unroll
      for (int nt = 0; nt < 4; ++nt)
        acc[jm][nt] = __builtin_amdgcn_mfma_f32_16x16x32_bf16(Af[jm][kc], Bf[nt], acc[jm][nt], 0, 0, 0);
  }

#pragma unroll
  for (int jm = 0; jm < 3; ++jm) {
    int Mt = w + 4 * jm;
    int l0 = Mt * 16 + (lane >> 4) * 4;
#pragma unroll
    for (int nt = 0; nt < 4; ++nt) {
      int o = nt * 16 + (lane & 15);
      int lp = l0 ^ ((o & 7) << 2);
      *(f32x4*)(ol + o * 192 + lp) = acc[jm][nt];
    }
  }
  __syncthreads();

  float* dst = out + (b * 64 * 128 + n) * 192;
#pragma unroll
  for (int j = 0; j < 12; ++j) {
    int f = j * 256 + t;
    int o = f / 48, g2 = f - o * 48;
    int lp = g2 * 4;
    int l = lp ^ ((o & 7) << 2);
    f32x4 v = *(const f32x4*)(ol + o * 192 + lp);
    *(f32x4*)(dst + o * (128 * 192) + l) = v;
  }
}

// ---------------------------------------------------------------------------
extern "C" void kernel_launch(void* const* d_in, const int* in_sizes, int n_in,
                              void* d_out, int out_size, void* d_ws, size_t ws_size,
                              hipStream_t stream) {
  const float* q  = (const float*)d_in[0];
  const float* wr = (const float*)d_in[1];
  const float* wi = (const float*)d_in[2];
  float* out = (float*)d_out;

  unsigned short* Xp = (unsigned short*)d_ws;            // 33.5 MB
  unsigned short* Yp = Xp + 16777216;                    // 33.5 MB

  hipFuncSetAttribute((const void*)k1d_dft, hipFuncAttributeMaxDynamicSharedMemorySize, 144896);
  hipFuncSetAttribute((const void*)k2m_mix, hipFuncAttributeMaxDynamicSharedMemorySize, 74240);
  hipFuncSetAttribute((const void*)k3_idft, hipFuncAttributeMaxDynamicSharedMemorySize, 57600);

  k1d_dft<<<dim3(512), dim3(512), 144896, stream>>>(q, Xp);
  k2m_mix<<<dim3(1024), dim3(512), 74240, stream>>>(wr, wi, Xp, Yp);
  k3_idft<<<dim3(4096), dim3(256), 57600, stream>>>(Yp, out);
}